// Round 1
// baseline (278.252 us; speedup 1.0000x reference)
//
#include <hip/hip_runtime.h>
#include <hip/hip_bf16.h>
#include <math.h>

// Problem constants
#define B 4
#define C 256
#define H 256
#define Wd 256
#define RD 93
#define NB 31
// sites per batch: 256 (s=16) + 64 (s=8) + 16 (s=4) = 336

// ---------------------------------------------------------------------------
// Kernel 1: pool x -> pool16 means (B,C,16,16). One block per (b,c) plane.
// Deterministic (shuffle + LDS tree reduction, no atomics).
// ---------------------------------------------------------------------------
__global__ __launch_bounds__(256) void pool_kernel(const float* __restrict__ x,
                                                   float* __restrict__ pool16) {
    int bc = blockIdx.x;            // b*C + c
    int t  = threadIdx.x;           // 0..255
    int w4 = t & 63;                // float4 column index (0..63)
    int wg = t >> 6;                // wave group 0..3

    const float4* xp = (const float4*)(x + (size_t)bc * (H * Wd));

    float acc[16];
#pragma unroll
    for (int i = 0; i < 16; ++i) {
        float a = 0.f;
#pragma unroll
        for (int rr = 0; rr < 4; ++rr) {
            int h = i * 16 + rr * 4 + wg;
            float4 v = xp[h * 64 + w4];
            a += (v.x + v.y) + (v.z + v.w);
        }
        acc[i] = a;
    }
    // reduce over 4-lane groups (lanes sharing the same pool column jj)
#pragma unroll
    for (int i = 0; i < 16; ++i) {
        acc[i] += __shfl_xor(acc[i], 1);
        acc[i] += __shfl_xor(acc[i], 2);
    }
    __shared__ float pp[4][256];
    int jj = w4 >> 2;
    if ((w4 & 3) == 0) {
#pragma unroll
        for (int i = 0; i < 16; ++i) pp[wg][i * 16 + jj] = acc[i];
    }
    __syncthreads();
    pool16[(size_t)bc * 256 + t] =
        (pp[0][t] + pp[1][t] + pp[2][t] + pp[3][t]) * (1.0f / 256.0f);
}

// ---------------------------------------------------------------------------
// Kernel 2: per (b, scale, site): pooled vec -> qkv -> attention -> out ->
// channel-mix with fusion_w slice -> y_s[b,o,site].  1344 blocks, 256 thr.
// ---------------------------------------------------------------------------
__global__ __launch_bounds__(256) void site_kernel(
    const float* __restrict__ pool16,
    const float* __restrict__ cw0, const float* __restrict__ cw1,
    const float* __restrict__ cw2,
    const float* __restrict__ sw0, const float* __restrict__ sw1,
    const float* __restrict__ sw2,
    const float* __restrict__ fusion_w,
    float* __restrict__ y4, float* __restrict__ y8, float* __restrict__ y16) {

    __shared__ float P[256];      // pooled input vector
    __shared__ float Wm[961];     // spectral 31x31
    __shared__ float QKV[279];
    __shared__ float QW[93];      // [g*31+m]
    __shared__ float A[9];        // attn [g*3+h]
    __shared__ float OUTV[93];

    int t = threadIdx.x;
    int blk = blockIdx.x;
    int b = blk / 336;
    int r = blk % 336;

    int s, site, foff;
    const float* cw; const float* sw; float* yout;
    if (r < 256)      { s = 16; site = r;       cw = cw2; sw = sw2; foff = 186; yout = y16; }
    else if (r < 320) { s = 8;  site = r - 256; cw = cw1; sw = sw1; foff = 93;  yout = y8;  }
    else              { s = 4;  site = r - 320; cw = cw0; sw = sw0; foff = 0;   yout = y4;  }
    int i = site / s, j = site % s;

    for (int idx = t; idx < 961; idx += 256) Wm[idx] = sw[idx];

    {   // pooled value for channel t at this site (derived from pool16 means)
        int f = 16 / s;                 // 1,2,4
        float acc = 0.f;
        int base = (b * 256 + t) * 256;
        for (int ii = 0; ii < f; ++ii)
            for (int jj = 0; jj < f; ++jj)
                acc += pool16[base + (i * f + ii) * 16 + (j * f + jj)];
        P[t] = acc / (float)(f * f);
    }
    __syncthreads();

    // qkv[o] = sum_c cw[o,c] * P[c]
    for (int o = t; o < 279; o += 256) {
        const float4* wrow = (const float4*)(cw + o * 256);
        float acc = 0.f;
#pragma unroll 8
        for (int c4 = 0; c4 < 64; ++c4) {
            float4 wv = wrow[c4];
            acc += wv.x * P[c4 * 4] + wv.y * P[c4 * 4 + 1] +
                   wv.z * P[c4 * 4 + 2] + wv.w * P[c4 * 4 + 3];
        }
        QKV[o] = acc;
    }
    __syncthreads();

    // QW[g,m] = sum_n q[g*31+n] * Wm[n,m]
    if (t < 93) {
        int g = t / 31, m = t % 31;
        float acc = 0.f;
        for (int n = 0; n < 31; ++n) acc += QKV[g * 31 + n] * Wm[n * 31 + m];
        QW[t] = acc;
    }
    __syncthreads();
    // attn[g,h] = scale * sum_m QW[g,m] * k[h*31+m]
    if (t < 9) {
        int g = t / 3, h = t % 3;
        float acc = 0.f;
        for (int m = 0; m < 31; ++m) acc += QW[g * 31 + m] * QKV[93 + h * 31 + m];
        A[t] = acc * 0.57735026918962576f;   // 3^-0.5
    }
    __syncthreads();
    if (t < 3) {   // softmax over h
        float a0 = A[t * 3], a1 = A[t * 3 + 1], a2 = A[t * 3 + 2];
        float mx = fmaxf(a0, fmaxf(a1, a2));
        float e0 = expf(a0 - mx), e1 = expf(a1 - mx), e2 = expf(a2 - mx);
        float inv = 1.0f / (e0 + e1 + e2);
        A[t * 3] = e0 * inv; A[t * 3 + 1] = e1 * inv; A[t * 3 + 2] = e2 * inv;
    }
    __syncthreads();
    // out[g*31+n] = sum_h A[g,h] * v[h*31+n]
    if (t < 93) {
        int g = t / 31, n = t % 31;
        OUTV[t] = A[g * 3] * QKV[186 + n] + A[g * 3 + 1] * QKV[186 + 31 + n] +
                  A[g * 3 + 2] * QKV[186 + 62 + n];
    }
    __syncthreads();
    // y[o] = sum_c fusion_w[o, foff+c] * out[c]
    {
        const float* fr = fusion_w + t * 279 + foff;
        float acc = 0.f;
#pragma unroll 31
        for (int c = 0; c < 93; ++c) acc += fr[c] * OUTV[c];
        yout[(size_t)(b * 256 + t) * (s * s) + site] = acc;
    }
}

// ---------------------------------------------------------------------------
// Kernel 3/5: fused interp + residual. STATS pass (WRITE=0) accumulates
// per-(b,c,hblk) sum/sumsq partials; WRITE pass normalizes and stores.
// Block = (b, c, hblk of 16 rows). 16384 blocks, 256 thr.
// ---------------------------------------------------------------------------
template <int WRITE>
__global__ __launch_bounds__(256) void fuse_kernel(
    const float* __restrict__ x,
    const float* __restrict__ ws_y4, const float* __restrict__ ws_y8,
    const float* __restrict__ ws_y16,
    const float* __restrict__ fusion_b,
    const float* __restrict__ gn_w, const float* __restrict__ gn_b,
    const float* __restrict__ stats_g,
    float* __restrict__ part, float* __restrict__ out) {

    __shared__ float ly16[256], ly8[64], ly4[16];
    __shared__ float2 rbd16[16][16];   // per row: (rb[j], rb[j+1 clamped])
    __shared__ float2 rbd8[16][8];
    __shared__ float2 rbd4[16][4];

    int blk = blockIdx.x;
    int hblk = blk & 15;
    int c = (blk >> 4) & 255;
    int b = blk >> 12;
    int t = threadIdx.x;

    // stage y planes
    ly16[t] = ws_y16[(size_t)(b * 256 + c) * 256 + t];
    if (t < 64) ly8[t] = ws_y8[(size_t)(b * 256 + c) * 64 + t];
    if (t < 16) ly4[t] = ws_y4[(size_t)(b * 256 + c) * 16 + t];
    __syncthreads();

    // h-blended rows for the 16 rows of this block (28 entries per row)
    for (int idx = t; idx < 448; idx += 256) {
        int r = idx / 28;
        int q = idx - r * 28;
        int h = hblk * 16 + r;
        if (q < 16) {
            float src = (h + 0.5f) * 0.0625f - 0.5f;
            src = fminf(fmaxf(src, 0.f), 15.f);
            int lo = (int)src; float wf = src - lo; int hi = min(lo + 1, 15);
            float rb = (1.f - wf) * ly16[lo * 16 + q] + wf * ly16[hi * 16 + q];
            rbd16[r][q].x = rb;
            if (q > 0) rbd16[r][q - 1].y = rb;
            if (q == 15) rbd16[r][15].y = rb;
        } else if (q < 24) {
            int jj = q - 16;
            float src = (h + 0.5f) * 0.03125f - 0.5f;
            src = fminf(fmaxf(src, 0.f), 7.f);
            int lo = (int)src; float wf = src - lo; int hi = min(lo + 1, 7);
            float rb = (1.f - wf) * ly8[lo * 8 + jj] + wf * ly8[hi * 8 + jj];
            rbd8[r][jj].x = rb;
            if (jj > 0) rbd8[r][jj - 1].y = rb;
            if (jj == 7) rbd8[r][7].y = rb;
        } else {
            int jj = q - 24;
            float src = (h + 0.5f) * 0.015625f - 0.5f;
            src = fminf(fmaxf(src, 0.f), 3.f);
            int lo = (int)src; float wf = src - lo; int hi = min(lo + 1, 3);
            float rb = (1.f - wf) * ly4[lo * 4 + jj] + wf * ly4[hi * 4 + jj];
            rbd4[r][jj].x = rb;
            if (jj > 0) rbd4[r][jj - 1].y = rb;
            if (jj == 3) rbd4[r][3].y = rb;
        }
    }
    __syncthreads();

    int w4 = t & 63;       // float4 column
    int wg = t >> 6;       // wave group
    int w0 = w4 * 4;

    // per-thread w-interp tables (fixed across all rows)
    int jlo16[4], jlo8[4], jlo4[4];
    float ww16[4], ww8[4], ww4[4];
#pragma unroll
    for (int p = 0; p < 4; ++p) {
        int w = w0 + p;
        float s16 = fminf(fmaxf((w + 0.5f) * 0.0625f - 0.5f, 0.f), 15.f);
        jlo16[p] = (int)s16; ww16[p] = s16 - jlo16[p];
        float s8 = fminf(fmaxf((w + 0.5f) * 0.03125f - 0.5f, 0.f), 7.f);
        jlo8[p] = (int)s8; ww8[p] = s8 - jlo8[p];
        float s4 = fminf(fmaxf((w + 0.5f) * 0.015625f - 0.5f, 0.f), 3.f);
        jlo4[p] = (int)s4; ww4[p] = s4 - jlo4[p];
    }

    float fb_c = fusion_b[c];
    float mean = 0.f, rstd = 0.f, gwc = 0.f, gbc = 0.f;
    if (WRITE) {
        int g = c >> 3;
        mean = stats_g[(b * 32 + g) * 2];
        rstd = stats_g[(b * 32 + g) * 2 + 1];
        gwc = gn_w[c]; gbc = gn_b[c];
    }

    const float4* xp = (const float4*)(x + (size_t)(b * 256 + c) * (H * Wd));
    float4* op = WRITE ? (float4*)(out + (size_t)(b * 256 + c) * (H * Wd)) : nullptr;

    float s0 = 0.f, s1 = 0.f;
#pragma unroll
    for (int it = 0; it < 4; ++it) {
        int r = it * 4 + wg;                    // row within block
        int idx4 = (hblk * 16 + r) * 64 + w4;   // float4 index in plane
        float4 xv = xp[idx4];
        float res[4];
        float px[4] = {xv.x, xv.y, xv.z, xv.w};
#pragma unroll
        for (int p = 0; p < 4; ++p) {
            float f = fb_c;
            float2 v16 = rbd16[r][jlo16[p]];
            f += (1.f - ww16[p]) * v16.x + ww16[p] * v16.y;
            float2 v8 = rbd8[r][jlo8[p]];
            f += (1.f - ww8[p]) * v8.x + ww8[p] * v8.y;
            float2 v4 = rbd4[r][jlo4[p]];
            f += (1.f - ww4[p]) * v4.x + ww4[p] * v4.y;
            float tv = px[p] + f;
            if (WRITE) {
                res[p] = (tv - mean) * rstd * gwc + gbc;
            } else {
                s0 += tv; s1 += tv * tv;
            }
        }
        if (WRITE) op[idx4] = make_float4(res[0], res[1], res[2], res[3]);
    }

    if (!WRITE) {
        // deterministic block reduction
#pragma unroll
        for (int off = 32; off > 0; off >>= 1) {
            s0 += __shfl_down(s0, off);
            s1 += __shfl_down(s1, off);
        }
        __shared__ float rs[4][2];
        if ((t & 63) == 0) { rs[t >> 6][0] = s0; rs[t >> 6][1] = s1; }
        __syncthreads();
        if (t == 0) {
            part[(size_t)blk * 2]     = rs[0][0] + rs[1][0] + rs[2][0] + rs[3][0];
            part[(size_t)blk * 2 + 1] = rs[0][1] + rs[1][1] + rs[2][1] + rs[3][1];
        }
    }
}

// ---------------------------------------------------------------------------
// Kernel 4: fold partials -> per-(b,group) mean/rstd (double accumulate).
// ---------------------------------------------------------------------------
__global__ __launch_bounds__(128) void gstats_kernel(const float* __restrict__ part,
                                                     float* __restrict__ stats_g) {
    int bg = blockIdx.x;            // b*32 + g
    int b = bg >> 5, g = bg & 31;
    int t = threadIdx.x;            // 0..127
    int c = g * 8 + (t >> 4);
    int hb = t & 15;
    size_t idx = ((size_t)(b * 256 + c) * 16 + hb) * 2;
    double s0 = (double)part[idx];
    double s1 = (double)part[idx + 1];
#pragma unroll
    for (int off = 32; off > 0; off >>= 1) {
        s0 += __shfl_down(s0, off);
        s1 += __shfl_down(s1, off);
    }
    __shared__ double sh[2][2];
    if ((t & 63) == 0) { sh[t >> 6][0] = s0; sh[t >> 6][1] = s1; }
    __syncthreads();
    if (t == 0) {
        double S0 = sh[0][0] + sh[1][0];
        double S1 = sh[0][1] + sh[1][1];
        const double N = 524288.0;   // 8 channels * 256 * 256
        double mean = S0 / N;
        double var = S1 / N - mean * mean;
        stats_g[bg * 2] = (float)mean;
        stats_g[bg * 2 + 1] = (float)(1.0 / sqrt(var + 1e-5));
    }
}

// ---------------------------------------------------------------------------
extern "C" void kernel_launch(void* const* d_in, const int* in_sizes, int n_in,
                              void* d_out, int out_size, void* d_ws, size_t ws_size,
                              hipStream_t stream) {
    const float* x   = (const float*)d_in[0];
    const float* cw0 = (const float*)d_in[1];
    const float* cw1 = (const float*)d_in[2];
    const float* cw2 = (const float*)d_in[3];
    const float* sw0 = (const float*)d_in[4];
    const float* sw1 = (const float*)d_in[5];
    const float* sw2 = (const float*)d_in[6];
    const float* fw  = (const float*)d_in[7];
    const float* fb  = (const float*)d_in[8];
    const float* gw  = (const float*)d_in[9];
    const float* gb  = (const float*)d_in[10];
    float* out = (float*)d_out;

    float* ws     = (float*)d_ws;
    float* pool16 = ws;                    // 4*256*256      = 262144
    float* y4     = pool16 + 262144;       // 4*256*16       = 16384
    float* y8     = y4 + 16384;            // 4*256*64       = 65536
    float* y16    = y8 + 65536;            // 4*256*256      = 262144
    float* part   = y16 + 262144;          // 16384*2        = 32768
    float* statsg = part + 32768;          // 128*2          = 256

    pool_kernel<<<B * C, 256, 0, stream>>>(x, pool16);
    site_kernel<<<B * 336, 256, 0, stream>>>(pool16, cw0, cw1, cw2,
                                             sw0, sw1, sw2, fw, y4, y8, y16);
    fuse_kernel<0><<<B * C * 16, 256, 0, stream>>>(x, y4, y8, y16, fb, gw, gb,
                                                   nullptr, part, nullptr);
    gstats_kernel<<<B * 32, 128, 0, stream>>>(part, statsg);
    fuse_kernel<1><<<B * C * 16, 256, 0, stream>>>(x, y4, y8, y16, fb, gw, gb,
                                                   statsg, nullptr, out);
}